// Round 1
// 201.774 us; speedup vs baseline: 1.0202x; 1.0202x over previous
//
#include <hip/hip_runtime.h>
#include <hip/hip_bf16.h>

// AttentionGrouping: B=4096 graphs, N=32 nodes, D=128, H=2 heads.
// Inputs fp32, outputs fp32: out=[B*N,128] then weight=[B*N,32,2] in d_out.
//
// R5: occupancy push. s_s (9216 B) now ALIASES the t_s region (t_s is dead
// after phase-2 MFMA reads; phase 2 computes into regs, barrier, then writes
// s_s over t_s). LDS 46592 -> 37376 B => 4 blocks/CU (16 waves/CU) instead
// of 3. Kernel was latency-bound: per-SIMD VALU issue ~16% (VALUBusy 58% is
// CU-aggregate of 4 SIMDs; MfmaUtil math confirms), occupancy 29%.
// Also: sparsemax inner loop 5->4 VALU/elem (select+fma form), pack_m/pack_v
// merged into one launch.

#define NG 4096

typedef short bf16x8 __attribute__((ext_vector_type(8)));
typedef float f32x4 __attribute__((ext_vector_type(4)));

__device__ inline short f2bf(float f) {
    __hip_bfloat16 h = __float2bfloat16(f);
    return __builtin_bit_cast(short, h);
}
__device__ inline unsigned pack2(float a, float b) {
    return (unsigned)(unsigned short)f2bf(a) | ((unsigned)(unsigned short)f2bf(b) << 16);
}

// packed_m[(mt*4+s)*512 + lane*8 + jj] = bf16( (1/16)*sum_c WQ[a][h*128+c]*WK[bl][h*128+c] )
//   h = mt>>3, a = s*32+(lane>>4)*8+jj (k-dim of T-mfma), bl = (mt&7)*16+(lane&15)
// This is the A-frag of M^T for T^T = M^T X^T.
// packed_v[(t*4+s)*512 + lane*8 + jj] = bf16(WV[s*32+(lane>>4)*8+jj][t*16+(lane&15)])
// B-frag of WV for V = X WV. Both packs fused into one launch (per-block
// uniform branch: blocks 0..127 do M, 128..255 do V).
__global__ void pack_mv_kernel(const float* __restrict__ WQ, const float* __restrict__ WK,
                               const float* __restrict__ WV,
                               short* __restrict__ pm, short* __restrict__ pv) {
    int gidx = blockIdx.x * 256 + threadIdx.x;    // 65536 total
    if (gidx < 32768) {
        int idx  = gidx;
        int jj   = idx & 7;
        int lane = (idx >> 3) & 63;
        int s    = (idx >> 9) & 3;
        int mt   = (idx >> 11) & 15;
        int h    = mt >> 3;
        int a    = s * 32 + (lane >> 4) * 8 + jj;
        int bl   = (mt & 7) * 16 + (lane & 15);
        const float4* qa = (const float4*)(WQ + a * 256 + h * 128);
        const float4* kb = (const float4*)(WK + bl * 256 + h * 128);
        float acc = 0.f;
        #pragma unroll 8
        for (int c = 0; c < 32; ++c) {
            float4 q4 = qa[c], k4 = kb[c];
            acc += q4.x * k4.x + q4.y * k4.y + q4.z * k4.z + q4.w * k4.w;
        }
        pm[idx] = f2bf(acc * 0.0625f);
    } else {
        int idx  = gidx - 32768;
        int jj   = idx & 7;
        int lane = (idx >> 3) & 63;
        int s    = (idx >> 9) & 3;
        int t    = (idx >> 11) & 15;
        int krow = s * 32 + (lane >> 4) * 8 + jj;
        int col  = t * 16 + (lane & 15);
        pv[idx] = f2bf(WV[krow * 256 + col]);
    }
}

__global__ __launch_bounds__(256, 4)
void fused_attn_kernel(const float* __restrict__ x, const short* __restrict__ pm,
                       const short* __restrict__ pv, float* __restrict__ out,
                       float* __restrict__ wgt) {
    __shared__ char __align__(16) smem[37376];
    short* t_s  = (short*)smem;               // T [32 node][264 d'] bf16, 16896 B (phases 1-2a)
    float* s_s  = (float*)smem;               // S [64 row][36 j] f32, 9216 B — ALIASES t_s (phase 2b+)
    short* vT_s = (short*)(smem + 16896);     // V^T [256 d'][40 node] bf16, 20480 B

    int b    = blockIdx.x;
    int tid  = threadIdx.x;
    int lane = tid & 63;
    int wave = tid >> 6;
    int lrow = lane & 15;
    int quad = lane >> 4;

    // ---- x -> register fragments (A-frag for V, B-frag for T/S transposed forms) ----
    bf16x8 xf[2][4];                          // [node-tile][k-chunk]
    const float* xg = x + (size_t)b * 4096;
    #pragma unroll
    for (int nt = 0; nt < 2; ++nt)
        #pragma unroll
        for (int s = 0; s < 4; ++s) {
            const float* p0 = &xg[(nt * 16 + lrow) * 128 + s * 32 + quad * 8];
            float4 f0 = *(const float4*)p0;
            float4 f1 = *(const float4*)(p0 + 4);
            bf16x8 v;
            v[0]=f2bf(f0.x); v[1]=f2bf(f0.y); v[2]=f2bf(f0.z); v[3]=f2bf(f0.w);
            v[4]=f2bf(f1.x); v[5]=f2bf(f1.y); v[6]=f2bf(f1.z); v[7]=f2bf(f1.w);
            xf[nt][s] = v;
        }

    // ---- phase 1a: T^T = M^T X^T -> t_s[node][d'] via packed b64 stores ----
    #pragma unroll
    for (int t = 0; t < 4; ++t) {
        int mt = wave * 4 + t;                // d'-tile 0..15 (head = mt>>3)
        const short* pb = pm + (mt * 4) * 512 + lane * 8;
        bf16x8 wf[4];
        #pragma unroll
        for (int s = 0; s < 4; ++s) wf[s] = *(const bf16x8*)&pb[s * 512];
        f32x4 acc[2] = {{0.f,0.f,0.f,0.f},{0.f,0.f,0.f,0.f}};
        #pragma unroll
        for (int nt = 0; nt < 2; ++nt)
            #pragma unroll
            for (int s = 0; s < 4; ++s)
                acc[nt] = __builtin_amdgcn_mfma_f32_16x16x32_bf16(wf[s], xf[nt][s], acc[nt], 0, 0, 0);
        #pragma unroll
        for (int nt = 0; nt < 2; ++nt) {
            int addr = (nt * 16 + lrow) * 264 + mt * 16 + quad * 4;
            uint2 pk; pk.x = pack2(acc[nt][0], acc[nt][1]); pk.y = pack2(acc[nt][2], acc[nt][3]);
            *(uint2*)&t_s[addr] = pk;
        }
    }
    // ---- phase 1b: V = X WV -> vT_s[d'][node] via packed b64 stores ----
    #pragma unroll
    for (int t = 0; t < 4; ++t) {
        int ntv = wave * 4 + t;               // col-tile 0..15
        const short* pb = pv + (ntv * 4) * 512 + lane * 8;
        bf16x8 wf[4];
        #pragma unroll
        for (int s = 0; s < 4; ++s) wf[s] = *(const bf16x8*)&pb[s * 512];
        f32x4 acc[2] = {{0.f,0.f,0.f,0.f},{0.f,0.f,0.f,0.f}};
        #pragma unroll
        for (int mt = 0; mt < 2; ++mt)
            #pragma unroll
            for (int s = 0; s < 4; ++s)
                acc[mt] = __builtin_amdgcn_mfma_f32_16x16x32_bf16(xf[mt][s], wf[s], acc[mt], 0, 0, 0);
        #pragma unroll
        for (int mt = 0; mt < 2; ++mt) {
            int addr = (ntv * 16 + lrow) * 40 + mt * 16 + quad * 4;
            uint2 pk; pk.x = pack2(acc[mt][0], acc[mt][1]); pk.y = pack2(acc[mt][2], acc[mt][3]);
            *(uint2*)&vT_s[addr] = pk;
        }
    }
    __syncthreads();

    // ---- phase 2a: S_h = T_h X^T (scale already in M) -> registers ----
    f32x4 sacc[2];
    #pragma unroll
    for (int tt = 0; tt < 2; ++tt) {
        int ti = wave * 2 + tt;               // 0..7 = h(2) x it(2) x jt(2)
        int h = ti >> 2, it = (ti >> 1) & 1, jt = ti & 1;
        f32x4 acc = {0.f, 0.f, 0.f, 0.f};
        #pragma unroll
        for (int s = 0; s < 4; ++s) {
            bf16x8 at = *(const bf16x8*)&t_s[(it * 16 + lrow) * 264 + h * 128 + s * 32 + quad * 8];
            acc = __builtin_amdgcn_mfma_f32_16x16x32_bf16(at, xf[jt][s], acc, 0, 0, 0);
        }
        sacc[tt] = acc;
    }
    __syncthreads();                          // all t_s reads done; safe to overwrite with s_s

    // ---- phase 2b: spill S to s_s (aliased over t_s) ----
    #pragma unroll
    for (int tt = 0; tt < 2; ++tt) {
        int ti = wave * 2 + tt;
        int h = ti >> 2, it = (ti >> 1) & 1, jt = ti & 1;
        #pragma unroll
        for (int r = 0; r < 4; ++r)
            s_s[(h * 32 + it * 16 + quad * 4 + r) * 36 + jt * 16 + lrow] = sacc[tt][r];
    }
    __syncthreads();

    // ---- phase 3: sparsemax, tau = max_k (cumsum_k - 1)/k ----
    // Lane (hh=lane>>5, j=lane&31) handles column j of row (hh*32 + i).
    // Each lane loads the full row (broadcast b128 reads), computes its own
    // rank and strict-greater prefix sum locally (select+fma form: 4 VALU/elem),
    // then a single 5-step shuffle max. Ties: strict compare (prob ~0 fp32).
    {
        int j  = lane & 31;
        int hh = lane >> 5;
        #pragma unroll
        for (int ii = 0; ii < 8; ++ii) {
            int i   = wave * 8 + ii;
            int row = hh * 32 + i;
            const float* zr = &s_s[row * 36];
            float z[32];
            #pragma unroll
            for (int c = 0; c < 8; ++c) {
                float4 f = *(const float4*)&zr[c * 4];
                z[c*4] = f.x; z[c*4+1] = f.y; z[c*4+2] = f.z; z[c*4+3] = f.w;
            }
            float zj = zr[j];
            float c0 = 0.f, c1 = 0.f, s0 = 0.f, s1 = 0.f;
            #pragma unroll
            for (int l = 0; l < 32; l += 2) {
                float m0 = (z[l]     > zj) ? 1.f : 0.f;
                float m1 = (z[l + 1] > zj) ? 1.f : 0.f;
                c0 += m0;  s0 = __builtin_fmaf(m0, z[l],     s0);
                c1 += m1;  s1 = __builtin_fmaf(m1, z[l + 1], s1);
            }
            float rk  = c0 + c1 + 1.f;            // this lane's rank k
            float cum = s0 + s1 + zj;             // cumsum of top-k
            float tc  = (cum - 1.f) / rk;         // tau_k
            #pragma unroll
            for (int m = 1; m <= 16; m <<= 1) tc = fmaxf(tc, __shfl_xor(tc, m, 32));
            float w = fmaxf(zj - tc, 0.f);
            ((short*)zr)[j] = f2bf(w);            // w row aliases S row start
            float wo = __shfl_xor(w, 32);         // pair heads for coalesced store
            if (lane < 32) {
                float2 v; v.x = w; v.y = wo;
                *(float2*)&wgt[((size_t)b * 32 + i) * 64 + j * 2] = v;
            }
        }
    }
    __syncthreads();

    // ---- phase 4: out = 0.5*(W_0 V_0 + W_1 V_1) ----
    #pragma unroll
    for (int tt = 0; tt < 4; ++tt) {
        int ti = wave * 4 + tt;               // 0..15 = it(2) x dt(8)
        int it = ti >> 3, dt = ti & 7;
        f32x4 acc = {0.f, 0.f, 0.f, 0.f};
        #pragma unroll
        for (int h = 0; h < 2; ++h) {
            bf16x8 aw = *(const bf16x8*)((short*)&s_s[(h * 32 + it * 16 + lrow) * 36] + quad * 8);
            bf16x8 bv = *(const bf16x8*)&vT_s[(h * 128 + dt * 16 + lrow) * 40 + quad * 8];
            acc = __builtin_amdgcn_mfma_f32_16x16x32_bf16(aw, bv, acc, 0, 0, 0);
        }
        #pragma unroll
        for (int r = 0; r < 4; ++r)
            out[((size_t)b * 32 + it * 16 + quad * 4 + r) * 128 + dt * 16 + lrow] = acc[r] * 0.5f;
    }
}

extern "C" void kernel_launch(void* const* d_in, const int* in_sizes, int n_in,
                              void* d_out, int out_size, void* d_ws, size_t ws_size,
                              hipStream_t stream) {
    const float* x  = (const float*)d_in[0];  // [4096,32,128] fp32
    const float* WK = (const float*)d_in[1];  // [128,256] fp32
    const float* WV = (const float*)d_in[2];
    const float* WQ = (const float*)d_in[3];
    float* out = (float*)d_out;               // [131072,128] fp32
    float* wgt = out + (size_t)NG * 32 * 128; // [131072,32,2] fp32
    short* pm = (short*)d_ws;                 // 32768 bf16 = 65536 B
    short* pv = pm + 32768;                   // 32768 bf16 = 65536 B

    hipLaunchKernelGGL(pack_mv_kernel, dim3(256), dim3(256), 0, stream, WQ, WK, WV, pm, pv);
    hipLaunchKernelGGL(fused_attn_kernel, dim3(NG), dim3(256), 0, stream, x, pm, pv, out, wgt);
}